// Round 3
// baseline (5309.689 us; speedup 1.0000x reference)
//
#include <hip/hip_runtime.h>

#define Bb 64
#define Tt 256
#define Cc 384
#define Ll 3
#define Hh 6
#define HD 64
#define Vv 65
#define FF 1536
#define NT (Bb*Tt)        // 16384 tokens
#define CQ 1152           // fused qkv width
#define LDP 72            // LDS row stride (u16): 144 B = multiple of 16

typedef unsigned short u16;
typedef unsigned int   u32;
typedef __attribute__((ext_vector_type(8))) short bf16x8;
typedef __attribute__((ext_vector_type(4))) short bf16x4;
typedef __attribute__((ext_vector_type(4))) float f32x4;

__device__ __forceinline__ float bf2f(u16 u) {
    u32 v = ((u32)u) << 16; float f; __builtin_memcpy(&f, &v, 4); return f;
}
__device__ __forceinline__ u16 f2bf(float f) {
    u32 u; __builtin_memcpy(&u, &f, 4);
    u = (u + 0x7fffu + ((u >> 16) & 1u)) >> 16;
    return (u16)u;
}

// ---------------- embedding: x = tok_emb[idx] + pos_emb (fp32 in, fp32 out) ----------------
__global__ void k_embed(const int* __restrict__ idx, const float* __restrict__ tok,
                        const float* __restrict__ pos, float* __restrict__ x)
{
    long i = (long)blockIdx.x * 256 + threadIdx.x;
    if (i >= (long)NT * Cc) return;
    int c  = (int)(i % Cc);
    int bt = (int)(i / Cc);
    int t  = bt % Tt;
    x[i] = tok[idx[bt] * Cc + c] + pos[t * Cc + c];
}

// ---------------- layernorm: fp32 in -> bf16 out, one wave per row ----------------
__global__ __launch_bounds__(256) void k_ln(const float* __restrict__ x,
    const float* __restrict__ g, const float* __restrict__ b, u16* __restrict__ h)
{
    int row  = (int)((blockIdx.x * 256 + threadIdx.x) >> 6);
    int lane = threadIdx.x & 63;
    const float* xr = x + (long)row * Cc;
    float v[6]; float s = 0.f;
    #pragma unroll
    for (int j = 0; j < 6; ++j) { v[j] = xr[lane + 64 * j]; s += v[j]; }
    #pragma unroll
    for (int m = 32; m; m >>= 1) s += __shfl_xor(s, m, 64);
    float mean = s * (1.f / 384.f);
    float q = 0.f;
    #pragma unroll
    for (int j = 0; j < 6; ++j) { float d = v[j] - mean; q += d * d; }
    #pragma unroll
    for (int m = 32; m; m >>= 1) q += __shfl_xor(q, m, 64);
    float rstd = rsqrtf(q * (1.f / 384.f) + 1e-5f);
    u16* hr = h + (long)row * Cc;
    #pragma unroll
    for (int j = 0; j < 6; ++j) {
        int c = lane + 64 * j;
        hr[c] = f2bf((v[j] - mean) * rstd * g[c] + b[c]);
    }
}

// ---------------- weight convert+transpose: Wt(bf16)[n*K+k] = W(f32)[k*N+n] ----------------
__global__ void k_cvtT(const float* __restrict__ W, u16* __restrict__ Wt, int K, int N)
{
    long i = (long)blockIdx.x * 256 + threadIdx.x;
    if (i >= (long)K * N) return;
    int k = (int)(i % K);
    int n = (int)(i / K);
    Wt[i] = f2bf(W[(long)k * N + n]);
}

// ---------------- GEMM: C[M,N] = epi(A[M,K] @ Bt[N,K]^T), A/Bt bf16, acc fp32 ----------------
// EPI 0: -> bf16, no bias; EPI 1: +bias, relu -> bf16; EPI 2: +bias, +R(f32) -> f32
template<int EPI>
__global__ __launch_bounds__(256) void k_gemm_bt(
    const u16* __restrict__ A, const u16* __restrict__ Bt,
    const float* __restrict__ bias, const float* __restrict__ R,
    void* __restrict__ Cout, int M, int N, int K)
{
    __shared__ u16 As[64][LDP];
    __shared__ u16 Bs[64][LDP];
    const int bm = blockIdx.x * 64;
    const int bn = blockIdx.y * 64;
    const int tid  = threadIdx.x;
    const int lane = tid & 63, wid = tid >> 6;
    const int wr = wid >> 1, wc = wid & 1;
    const int lrow = tid >> 2;
    const int lcol = (tid & 3) * 8;
    const int r  = lane & 15;
    const int kk = (lane >> 4) * 8;
    f32x4 acc[2][2] = {};
    const u16* Ap = A  + (long)(bm + lrow) * K + lcol;
    const u16* Bp = Bt + (long)(bn + lrow) * K + lcol;
    for (int k0 = 0; k0 < K; k0 += 32) {
        *(bf16x8*)&As[lrow][lcol] = *(const bf16x8*)(Ap + k0);
        *(bf16x8*)&Bs[lrow][lcol] = *(const bf16x8*)(Bp + k0);
        __syncthreads();
        bf16x8 a0 = *(const bf16x8*)&As[wr * 32 + r][kk];
        bf16x8 a1 = *(const bf16x8*)&As[wr * 32 + 16 + r][kk];
        bf16x8 b0 = *(const bf16x8*)&Bs[wc * 32 + r][kk];
        bf16x8 b1 = *(const bf16x8*)&Bs[wc * 32 + 16 + r][kk];
        acc[0][0] = __builtin_amdgcn_mfma_f32_16x16x32_bf16(a0, b0, acc[0][0], 0, 0, 0);
        acc[0][1] = __builtin_amdgcn_mfma_f32_16x16x32_bf16(a0, b1, acc[0][1], 0, 0, 0);
        acc[1][0] = __builtin_amdgcn_mfma_f32_16x16x32_bf16(a1, b0, acc[1][0], 0, 0, 0);
        acc[1][1] = __builtin_amdgcn_mfma_f32_16x16x32_bf16(a1, b1, acc[1][1], 0, 0, 0);
        __syncthreads();
    }
    #pragma unroll
    for (int mi = 0; mi < 2; ++mi)
    #pragma unroll
    for (int ni = 0; ni < 2; ++ni)
    #pragma unroll
    for (int i = 0; i < 4; ++i) {
        int row = bm + wr * 32 + mi * 16 + (lane >> 4) * 4 + i;
        int col = bn + wc * 32 + ni * 16 + (lane & 15);
        float v = acc[mi][ni][i];
        if constexpr (EPI >= 1) v += bias[col];
        if constexpr (EPI == 1) v = fmaxf(v, 0.f);
        if constexpr (EPI == 2) {
            long o = (long)row * N + col;
            ((float*)Cout)[o] = v + R[o];
        } else {
            ((u16*)Cout)[(long)row * N + col] = f2bf(v);
        }
    }
}

// ---------------- attention: one block per (b, head), qkv fused layout (bf16) ----------------
__global__ __launch_bounds__(256) void k_attn(const u16* __restrict__ qkv, u16* __restrict__ att)
{
    __shared__ u16 ks[Tt][LDP];
    __shared__ u16 vs[Tt][LDP];
    int bh = blockIdx.x;
    int b = bh / Hh, hh = bh % Hh;
    int tid = threadIdx.x, lane = tid & 63, w = tid >> 6;
    long qbase = (long)(b * Tt) * CQ + hh * HD;
    {
        const u16* kg = qkv + qbase + Cc     + (long)tid * CQ;
        const u16* vg = qkv + qbase + 2 * Cc + (long)tid * CQ;
        #pragma unroll
        for (int c = 0; c < HD; c += 8) {
            *(bf16x8*)&ks[tid][c] = *(const bf16x8*)&kg[c];
            *(bf16x8*)&vs[tid][c] = *(const bf16x8*)&vg[c];
        }
    }
    __syncthreads();
    const float scale = 0.051031036307982884f;   // 384^-0.5 (full C, per reference)
    for (int tl = 0; tl < 64; ++tl) {
        int t = w * 64 + tl;
        const u16* qr = qkv + qbase + (long)t * CQ;
        float sc[4] = {0.f, 0.f, 0.f, 0.f};
        #pragma unroll
        for (int c = 0; c < HD; c += 4) {
            bf16x4 qc = *(const bf16x4*)&qr[c];
            float q0 = bf2f((u16)qc[0]), q1 = bf2f((u16)qc[1]);
            float q2 = bf2f((u16)qc[2]), q3 = bf2f((u16)qc[3]);
            #pragma unroll
            for (int j = 0; j < 4; ++j) {
                bf16x4 kc = *(const bf16x4*)&ks[j * 64 + lane][c];
                sc[j] += q0 * bf2f((u16)kc[0]) + q1 * bf2f((u16)kc[1])
                       + q2 * bf2f((u16)kc[2]) + q3 * bf2f((u16)kc[3]);
            }
        }
        float m = -3.0e38f;
        #pragma unroll
        for (int j = 0; j < 4; ++j) {
            sc[j] = (j * 64 + lane <= t) ? sc[j] * scale : -3.0e38f;
            m = fmaxf(m, sc[j]);
        }
        #pragma unroll
        for (int mm = 32; mm; mm >>= 1) m = fmaxf(m, __shfl_xor(m, mm, 64));
        float sum = 0.f;
        #pragma unroll
        for (int j = 0; j < 4; ++j) { sc[j] = __expf(sc[j] - m); sum += sc[j]; }
        #pragma unroll
        for (int mm = 32; mm; mm >>= 1) sum += __shfl_xor(sum, mm, 64);
        float inv = 1.f / sum;
        float out = 0.f;
        #pragma unroll
        for (int j = 0; j < 4; ++j) {           // static index into sc[] (no scratch)
            int s0 = j * 64;
            if (s0 <= t) {
                float pj = sc[j];
                int send = t - s0; if (send > 63) send = 63;
                for (int sl = 0; sl <= send; ++sl) {
                    float ps = __shfl(pj, sl, 64);
                    out += ps * bf2f(vs[s0 + sl][lane]);
                }
            }
        }
        att[(long)(b * Tt + t) * Cc + hh * HD + lane] = f2bf(out * inv);
    }
}

// ---------------- lm head: 4 rows/block, wave per row, out fp32 ----------------
__global__ __launch_bounds__(256) void k_lmhead(const u16* __restrict__ h,
    const u16* __restrict__ WT /* [Vv][Cc] bf16 */, const float* __restrict__ blm,
    float* __restrict__ out)
{
    __shared__ u16 hs[4][Cc];
    const int tid = threadIdx.x;
    const int row0 = blockIdx.x * 4;
    if (tid < 192) {                     // stage 4 rows: 192 × bf16x8
        int r = tid / 48, c = (tid % 48) * 8;
        *(bf16x8*)&hs[r][c] = *(const bf16x8*)&h[(long)(row0 + r) * Cc + c];
    }
    __syncthreads();
    const int w = tid >> 6, lane = tid & 63;
    const int row = row0 + w;
    for (int j = lane; j < Vv; j += 64) {
        const u16* wr = WT + (long)j * Cc;
        float acc = 0.f;
        for (int c = 0; c < Cc; c += 8) {
            bf16x8 hv = *(const bf16x8*)&hs[w][c];
            bf16x8 wv = *(const bf16x8*)&wr[c];
            #pragma unroll
            for (int e = 0; e < 8; ++e) acc += bf2f((u16)hv[e]) * bf2f((u16)wv[e]);
        }
        out[(long)row * Vv + j] = acc + blm[j];
    }
}

extern "C" void kernel_launch(void* const* d_in, const int* in_sizes, int n_in,
                              void* d_out, int out_size, void* d_ws, size_t ws_size,
                              hipStream_t stream)
{
    (void)in_sizes; (void)n_in; (void)out_size; (void)ws_size;
    const int*   idx  = (const int*)d_in[0];
    const float* tok  = (const float*)d_in[1];
    const float* pos  = (const float*)d_in[2];
    const float* Wq   = (const float*)d_in[3];
    const float* Wk   = (const float*)d_in[4];
    const float* Wv   = (const float*)d_in[5];
    const float* Wo   = (const float*)d_in[6];
    const float* bo   = (const float*)d_in[7];
    const float* ln1g = (const float*)d_in[8];
    const float* ln1b = (const float*)d_in[9];
    const float* ln2g = (const float*)d_in[10];
    const float* ln2b = (const float*)d_in[11];
    const float* W1   = (const float*)d_in[12];
    const float* b1   = (const float*)d_in[13];
    const float* W2   = (const float*)d_in[14];
    const float* b2   = (const float*)d_in[15];
    const float* lnfg = (const float*)d_in[16];
    const float* lnfb = (const float*)d_in[17];
    const float* Wlm  = (const float*)d_in[18];
    const float* blm  = (const float*)d_in[19];

    // workspace carve-outs (256B aligned); qkvb and fb alias (never both live)
    char* w = (char*)d_ws;
    auto carve = [&](size_t bytes) { char* p = w; w += (bytes + 255) & ~(size_t)255; return p; };
    float* x   = (float*)carve((size_t)NT * Cc * 4);
    u16*  big  = (u16*)carve((size_t)NT * FF * 2);
    u16*  h    = (u16*)carve((size_t)NT * Cc * 2);
    u16*  ab   = (u16*)carve((size_t)NT * Cc * 2);
    u16*  Wqkvt= (u16*)carve((size_t)Ll * CQ * Cc * 2);
    u16*  Wot  = (u16*)carve((size_t)Ll * Cc * Cc * 2);
    u16*  W1t  = (u16*)carve((size_t)Ll * FF * Cc * 2);
    u16*  W2t  = (u16*)carve((size_t)Ll * Cc * FF * 2);
    u16*  Wlmt = (u16*)carve((size_t)Vv * Cc * 2);
    u16*  qkvb = big;
    u16*  fb   = big;

    const int TPB = 256;
    for (int l = 0; l < Ll; ++l) {
        u16* qt = Wqkvt + (size_t)l * CQ * Cc;
        k_cvtT<<<(Cc * Cc + 255) / 256, TPB, 0, stream>>>(Wq + (size_t)l * Cc * Cc, qt,               Cc, Cc);
        k_cvtT<<<(Cc * Cc + 255) / 256, TPB, 0, stream>>>(Wk + (size_t)l * Cc * Cc, qt + Cc * Cc,     Cc, Cc);
        k_cvtT<<<(Cc * Cc + 255) / 256, TPB, 0, stream>>>(Wv + (size_t)l * Cc * Cc, qt + 2 * Cc * Cc, Cc, Cc);
        k_cvtT<<<(Cc * Cc + 255) / 256, TPB, 0, stream>>>(Wo + (size_t)l * Cc * Cc, Wot + (size_t)l * Cc * Cc, Cc, Cc);
        k_cvtT<<<(Cc * FF + 255) / 256, TPB, 0, stream>>>(W1 + (size_t)l * Cc * FF, W1t + (size_t)l * FF * Cc, Cc, FF);
        k_cvtT<<<(Cc * FF + 255) / 256, TPB, 0, stream>>>(W2 + (size_t)l * FF * Cc, W2t + (size_t)l * Cc * FF, FF, Cc);
    }
    k_cvtT<<<(Cc * Vv + 255) / 256, TPB, 0, stream>>>(Wlm, Wlmt, Cc, Vv);

    k_embed<<<((long)NT * Cc + 255) / 256, TPB, 0, stream>>>(idx, tok, pos, x);

    for (int l = 0; l < Ll; ++l) {
        k_ln<<<NT / 4, TPB, 0, stream>>>(x, ln1g + l * Cc, ln1b + l * Cc, h);
        dim3 gqkv(NT / 64, CQ / 64);
        k_gemm_bt<0><<<gqkv, TPB, 0, stream>>>(h, Wqkvt + (size_t)l * CQ * Cc,
                                               nullptr, nullptr, qkvb, NT, CQ, Cc);
        k_attn<<<Bb * Hh, TPB, 0, stream>>>(qkvb, ab);
        dim3 go(NT / 64, Cc / 64);
        k_gemm_bt<2><<<go, TPB, 0, stream>>>(ab, Wot + (size_t)l * Cc * Cc,
                                             bo + l * Cc, x, x, NT, Cc, Cc);
        k_ln<<<NT / 4, TPB, 0, stream>>>(x, ln2g + l * Cc, ln2b + l * Cc, h);
        dim3 g1(NT / 64, FF / 64);
        k_gemm_bt<1><<<g1, TPB, 0, stream>>>(h, W1t + (size_t)l * FF * Cc,
                                             b1 + l * FF, nullptr, fb, NT, FF, Cc);
        dim3 g2(NT / 64, Cc / 64);
        k_gemm_bt<2><<<g2, TPB, 0, stream>>>(fb, W2t + (size_t)l * Cc * FF,
                                             b2 + l * Cc, x, x, NT, Cc, FF);
    }
    k_ln<<<NT / 4, TPB, 0, stream>>>(x, lnfg, lnfb, h);
    k_lmhead<<<NT / 4, TPB, 0, stream>>>(h, Wlmt, blm, (float*)d_out);
}

// Round 6
// 739.382 us; speedup vs baseline: 7.1813x; 7.1813x over previous
//
#include <hip/hip_runtime.h>

#define Bb 64
#define Tt 256
#define Cc 384
#define Ll 3
#define Hh 6
#define HD 64
#define Vv 65
#define FF 1536
#define NT (Bb*Tt)        // 16384 tokens
#define CQ 1152           // fused qkv width
#define LDP 72            // LDS row stride (u16): 144 B = multiple of 16

typedef unsigned short u16;
typedef unsigned int   u32;
typedef __attribute__((ext_vector_type(8))) short bf16x8;
typedef __attribute__((ext_vector_type(4))) short bf16x4;
typedef __attribute__((ext_vector_type(4))) float f32x4;

__device__ __forceinline__ float bf2f(u16 u) {
    u32 v = ((u32)u) << 16; float f; __builtin_memcpy(&f, &v, 4); return f;
}
__device__ __forceinline__ u16 f2bf(float f) {
    u32 u; __builtin_memcpy(&u, &f, 4);
    u = (u + 0x7fffu + ((u >> 16) & 1u)) >> 16;
    return (u16)u;
}

// ---------------- embedding ----------------
__global__ void k_embed(const int* __restrict__ idx, const float* __restrict__ tok,
                        const float* __restrict__ pos, float* __restrict__ x)
{
    long i = (long)blockIdx.x * 256 + threadIdx.x;
    if (i >= (long)NT * Cc) return;
    int c  = (int)(i % Cc);
    int bt = (int)(i / Cc);
    int t  = bt % Tt;
    x[i] = tok[idx[bt] * Cc + c] + pos[t * Cc + c];
}

// ---------------- layernorm: fp32 in -> bf16 out, one wave per row ----------------
__global__ __launch_bounds__(256) void k_ln(const float* __restrict__ x,
    const float* __restrict__ g, const float* __restrict__ b, u16* __restrict__ h)
{
    int row  = (int)((blockIdx.x * 256 + threadIdx.x) >> 6);
    int lane = threadIdx.x & 63;
    const float* xr = x + (long)row * Cc;
    float v[6]; float s = 0.f;
    #pragma unroll
    for (int j = 0; j < 6; ++j) { v[j] = xr[lane + 64 * j]; s += v[j]; }
    #pragma unroll
    for (int m = 32; m; m >>= 1) s += __shfl_xor(s, m, 64);
    float mean = s * (1.f / 384.f);
    float q = 0.f;
    #pragma unroll
    for (int j = 0; j < 6; ++j) { float d = v[j] - mean; q += d * d; }
    #pragma unroll
    for (int m = 32; m; m >>= 1) q += __shfl_xor(q, m, 64);
    float rstd = rsqrtf(q * (1.f / 384.f) + 1e-5f);
    u16* hr = h + (long)row * Cc;
    #pragma unroll
    for (int j = 0; j < 6; ++j) {
        int c = lane + 64 * j;
        hr[c] = f2bf((v[j] - mean) * rstd * g[c] + b[c]);
    }
}

// ---------------- tiled convert+transpose: Wt(bf16)[n*K+k] = W(f32)[k*N+n] ----------------
__global__ __launch_bounds__(256) void k_cvtT32(const float* __restrict__ W, u16* __restrict__ Wt,
                                                int K, int N)
{
    __shared__ u16 tile[32][33];
    const int kt = blockIdx.x * 32, nt = blockIdx.y * 32;
    const int tx = threadIdx.x & 31, ty = threadIdx.x >> 5;   // 32 x 8
    #pragma unroll
    for (int r = 0; r < 4; ++r) {
        int k = kt + ty + 8 * r;
        tile[ty + 8 * r][tx] = f2bf(W[(long)k * N + nt + tx]);   // coalesced read
    }
    __syncthreads();
    #pragma unroll
    for (int r = 0; r < 4; ++r) {
        int n = nt + ty + 8 * r;
        Wt[(long)n * K + kt + tx] = tile[tx][ty + 8 * r];        // coalesced write
    }
}
// scalar fallback (Wlm: N=65)
__global__ void k_cvtT(const float* __restrict__ W, u16* __restrict__ Wt, int K, int N)
{
    long i = (long)blockIdx.x * 256 + threadIdx.x;
    if (i >= (long)K * N) return;
    int k = (int)(i % K);
    int n = (int)(i / K);
    Wt[i] = f2bf(W[(long)k * N + n]);
}

// ---------------- GEMM: C[M,N] = epi(A[M,K] @ Bt[N,K]^T), A/Bt bf16, acc fp32 ----------------
// EPI 0: -> bf16; EPI 1: +bias, relu -> bf16; EPI 2: +bias, +R(f32) -> f32
template<int EPI>
__global__ __launch_bounds__(256) void k_gemm_bt(
    const u16* __restrict__ A, const u16* __restrict__ Bt,
    const float* __restrict__ bias, const float* __restrict__ R,
    void* __restrict__ Cout, int M, int N, int K)
{
    __shared__ u16 As[64][LDP];
    __shared__ u16 Bs[64][LDP];
    const int bm = blockIdx.x * 64;
    const int bn = blockIdx.y * 64;
    const int tid  = threadIdx.x;
    const int lane = tid & 63, wid = tid >> 6;
    const int wr = wid >> 1, wc = wid & 1;
    const int lrow = tid >> 2;
    const int lcol = (tid & 3) * 8;
    const int r  = lane & 15;
    const int kk = (lane >> 4) * 8;
    f32x4 acc[2][2] = {};
    const u16* Ap = A  + (long)(bm + lrow) * K + lcol;
    const u16* Bp = Bt + (long)(bn + lrow) * K + lcol;
    for (int k0 = 0; k0 < K; k0 += 32) {
        *(bf16x8*)&As[lrow][lcol] = *(const bf16x8*)(Ap + k0);
        *(bf16x8*)&Bs[lrow][lcol] = *(const bf16x8*)(Bp + k0);
        __syncthreads();
        bf16x8 a0 = *(const bf16x8*)&As[wr * 32 + r][kk];
        bf16x8 a1 = *(const bf16x8*)&As[wr * 32 + 16 + r][kk];
        bf16x8 b0 = *(const bf16x8*)&Bs[wc * 32 + r][kk];
        bf16x8 b1 = *(const bf16x8*)&Bs[wc * 32 + 16 + r][kk];
        acc[0][0] = __builtin_amdgcn_mfma_f32_16x16x32_bf16(a0, b0, acc[0][0], 0, 0, 0);
        acc[0][1] = __builtin_amdgcn_mfma_f32_16x16x32_bf16(a0, b1, acc[0][1], 0, 0, 0);
        acc[1][0] = __builtin_amdgcn_mfma_f32_16x16x32_bf16(a1, b0, acc[1][0], 0, 0, 0);
        acc[1][1] = __builtin_amdgcn_mfma_f32_16x16x32_bf16(a1, b1, acc[1][1], 0, 0, 0);
        __syncthreads();
    }
    #pragma unroll
    for (int mi = 0; mi < 2; ++mi)
    #pragma unroll
    for (int ni = 0; ni < 2; ++ni)
    #pragma unroll
    for (int i = 0; i < 4; ++i) {
        int row = bm + wr * 32 + mi * 16 + (lane >> 4) * 4 + i;
        int col = bn + wc * 32 + ni * 16 + (lane & 15);
        float v = acc[mi][ni][i];
        if constexpr (EPI >= 1) v += bias[col];
        if constexpr (EPI == 1) v = fmaxf(v, 0.f);
        if constexpr (EPI == 2) {
            long o = (long)row * N + col;
            ((float*)Cout)[o] = v + R[o];
        } else {
            ((u16*)Cout)[(long)row * N + col] = f2bf(v);
        }
    }
}

// ---------------- MFMA flash attention ----------------
// grid (qt=4, h=6, b=64), 256 threads = 4 waves, each wave owns 16 q-rows
__global__ __launch_bounds__(256) void k_attn_mfma(const u16* __restrict__ qkv,
                                                   u16* __restrict__ att)
{
    __shared__ __align__(16) u16 ks[64][LDP];       // K-tile  [key][d]
    __shared__ __align__(16) u16 vt[64][LDP];       // V-tile^T [d][key]
    __shared__ __align__(16) u16 pt[4][16][LDP];    // per-wave P [qrow][key]
    const int qt = blockIdx.x, hh = blockIdx.y, b = blockIdx.z;
    const int tid = threadIdx.x, lane = tid & 63, w = tid >> 6;
    const int l15 = lane & 15, g = lane >> 4;
    const int q0 = qt * 64;
    const long tokbase = (long)b * Tt;
    const float scale = 0.051031036307982884f;      // 384^-0.5 (full C per reference)

    // Q fragments (A-layout): row = w*16 + l15, k(d) = g*8+j (+32 for second half)
    bf16x8 qa0, qa1;
    {
        const u16* qp = qkv + (tokbase + q0 + w * 16 + l15) * CQ + hh * HD + g * 8;
        qa0 = *(const bf16x8*)(qp);
        qa1 = *(const bf16x8*)(qp + 32);
    }
    f32x4 o[4] = {};                               // o[dtile][i]; C-layout row = g*4+i
    float mrow[4] = {-1e30f, -1e30f, -1e30f, -1e30f};
    float lrow[4] = {0.f, 0.f, 0.f, 0.f};

    for (int kt = 0; kt <= qt; ++kt) {
        // ---- stage K (row-major) and V (transposed) ----
        {
            int key = tid >> 2, c0 = (tid & 3) * 16;
            const u16* kg = qkv + (tokbase + kt * 64 + key) * CQ + Cc     + hh * HD + c0;
            const u16* vg = qkv + (tokbase + kt * 64 + key) * CQ + 2 * Cc + hh * HD + c0;
            *(bf16x8*)&ks[key][c0]     = *(const bf16x8*)kg;
            *(bf16x8*)&ks[key][c0 + 8] = *(const bf16x8*)(kg + 8);
            bf16x8 v0 = *(const bf16x8*)vg;
            bf16x8 v1 = *(const bf16x8*)(vg + 8);
            #pragma unroll
            for (int j = 0; j < 8; ++j) vt[c0 + j][key]     = (u16)v0[j];
            #pragma unroll
            for (int j = 0; j < 8; ++j) vt[c0 + 8 + j][key] = (u16)v1[j];
        }
        __syncthreads();
        // ---- QK^T: 16x64 scores per wave; C-layout col = l15, row = g*4+i ----
        f32x4 s[4] = {};
        #pragma unroll
        for (int c = 0; c < 4; ++c) {
            bf16x8 kb0 = *(const bf16x8*)&ks[c * 16 + l15][g * 8];
            bf16x8 kb1 = *(const bf16x8*)&ks[c * 16 + l15][32 + g * 8];
            s[c] = __builtin_amdgcn_mfma_f32_16x16x32_bf16(qa0, kb0, s[c], 0, 0, 0);
            s[c] = __builtin_amdgcn_mfma_f32_16x16x32_bf16(qa1, kb1, s[c], 0, 0, 0);
        }
        // ---- scale + causal mask (diagonal tile only) ----
        const bool diag = (kt == qt);
        #pragma unroll
        for (int c = 0; c < 4; ++c)
        #pragma unroll
        for (int i = 0; i < 4; ++i) {
            float v = s[c][i] * scale;
            if (diag && (c * 16 + l15 > w * 16 + 4 * g + i)) v = -1e30f;
            s[c][i] = v;
        }
        // ---- online softmax: row r = g*4+i owned by 16 lanes (same g, all l15) ----
        #pragma unroll
        for (int i = 0; i < 4; ++i) {
            float m0 = fmaxf(fmaxf(s[0][i], s[1][i]), fmaxf(s[2][i], s[3][i]));
            #pragma unroll
            for (int mm = 1; mm < 16; mm <<= 1) m0 = fmaxf(m0, __shfl_xor(m0, mm, 64));
            float mn = fmaxf(mrow[i], m0);
            float alpha = __expf(mrow[i] - mn);
            mrow[i] = mn;
            float sum = 0.f;
            #pragma unroll
            for (int c = 0; c < 4; ++c) {
                float p = __expf(s[c][i] - mn);
                s[c][i] = p;
                sum += p;
            }
            #pragma unroll
            for (int mm = 1; mm < 16; mm <<= 1) sum += __shfl_xor(sum, mm, 64);
            lrow[i] = lrow[i] * alpha + sum;
            #pragma unroll
            for (int d = 0; d < 4; ++d) o[d][i] *= alpha;    // per-row rescale
        }
        // ---- P: C-layout -> A-layout via per-wave LDS buffer ----
        #pragma unroll
        for (int c = 0; c < 4; ++c)
        #pragma unroll
        for (int i = 0; i < 4; ++i)
            pt[w][g * 4 + i][c * 16 + l15] = f2bf(s[c][i]);
        bf16x8 pa0 = *(const bf16x8*)&pt[w][l15][g * 8];
        bf16x8 pa1 = *(const bf16x8*)&pt[w][l15][32 + g * 8];
        // ---- PV: o[16x64] += P @ V (B-frag from vt: row d, col key) ----
        #pragma unroll
        for (int d = 0; d < 4; ++d) {
            bf16x8 vb0 = *(const bf16x8*)&vt[d * 16 + l15][g * 8];
            bf16x8 vb1 = *(const bf16x8*)&vt[d * 16 + l15][32 + g * 8];
            o[d] = __builtin_amdgcn_mfma_f32_16x16x32_bf16(pa0, vb0, o[d], 0, 0, 0);
            o[d] = __builtin_amdgcn_mfma_f32_16x16x32_bf16(pa1, vb1, o[d], 0, 0, 0);
        }
        __syncthreads();
    }
    #pragma unroll
    for (int i = 0; i < 4; ++i) {
        float inv = 1.f / lrow[i];
        int row = q0 + w * 16 + g * 4 + i;
        u16* ap = att + (tokbase + row) * Cc + hh * HD;
        #pragma unroll
        for (int d = 0; d < 4; ++d)
            ap[d * 16 + l15] = f2bf(o[d][i] * inv);
    }
}

// ---------------- lm head ----------------
__global__ __launch_bounds__(256) void k_lmhead(const u16* __restrict__ h,
    const u16* __restrict__ WT, const float* __restrict__ blm, float* __restrict__ out)
{
    __shared__ u16 hs[4][Cc];
    const int tid = threadIdx.x;
    const int row0 = blockIdx.x * 4;
    if (tid < 192) {
        int r = tid / 48, c = (tid % 48) * 8;
        *(bf16x8*)&hs[r][c] = *(const bf16x8*)&h[(long)(row0 + r) * Cc + c];
    }
    __syncthreads();
    const int w = tid >> 6, lane = tid & 63;
    const int row = row0 + w;
    for (int j = lane; j < Vv; j += 64) {
        const u16* wr = WT + (long)j * Cc;
        float acc = 0.f;
        for (int c = 0; c < Cc; c += 8) {
            bf16x8 hv = *(const bf16x8*)&hs[w][c];
            bf16x8 wv = *(const bf16x8*)&wr[c];
            #pragma unroll
            for (int e = 0; e < 8; ++e) acc += bf2f((u16)hv[e]) * bf2f((u16)wv[e]);
        }
        out[(long)row * Vv + j] = acc + blm[j];
    }
}

extern "C" void kernel_launch(void* const* d_in, const int* in_sizes, int n_in,
                              void* d_out, int out_size, void* d_ws, size_t ws_size,
                              hipStream_t stream)
{
    (void)in_sizes; (void)n_in; (void)out_size; (void)ws_size;
    const int*   idx  = (const int*)d_in[0];
    const float* tok  = (const float*)d_in[1];
    const float* pos  = (const float*)d_in[2];
    const float* Wq   = (const float*)d_in[3];
    const float* Wk   = (const float*)d_in[4];
    const float* Wv   = (const float*)d_in[5];
    const float* Wo   = (const float*)d_in[6];
    const float* bo   = (const float*)d_in[7];
    const float* ln1g = (const float*)d_in[8];
    const float* ln1b = (const float*)d_in[9];
    const float* ln2g = (const float*)d_in[10];
    const float* ln2b = (const float*)d_in[11];
    const float* W1   = (const float*)d_in[12];
    const float* b1   = (const float*)d_in[13];
    const float* W2   = (const float*)d_in[14];
    const float* b2   = (const float*)d_in[15];
    const float* lnfg = (const float*)d_in[16];
    const float* lnfb = (const float*)d_in[17];
    const float* Wlm  = (const float*)d_in[18];
    const float* blm  = (const float*)d_in[19];

    char* w = (char*)d_ws;
    auto carve = [&](size_t bytes) { char* p = w; w += (bytes + 255) & ~(size_t)255; return p; };
    float* x   = (float*)carve((size_t)NT * Cc * 4);
    u16*  big  = (u16*)carve((size_t)NT * FF * 2);
    u16*  h    = (u16*)carve((size_t)NT * Cc * 2);
    u16*  ab   = (u16*)carve((size_t)NT * Cc * 2);
    u16*  Wqkvt= (u16*)carve((size_t)Ll * CQ * Cc * 2);
    u16*  Wot  = (u16*)carve((size_t)Ll * Cc * Cc * 2);
    u16*  W1t  = (u16*)carve((size_t)Ll * FF * Cc * 2);
    u16*  W2t  = (u16*)carve((size_t)Ll * Cc * FF * 2);
    u16*  Wlmt = (u16*)carve((size_t)Vv * Cc * 2);
    u16*  qkvb = big;
    u16*  fb   = big;

    const int TPB = 256;
    for (int l = 0; l < Ll; ++l) {
        u16* qt = Wqkvt + (size_t)l * CQ * Cc;
        k_cvtT32<<<dim3(Cc/32, Cc/32), TPB, 0, stream>>>(Wq + (size_t)l * Cc * Cc, qt,               Cc, Cc);
        k_cvtT32<<<dim3(Cc/32, Cc/32), TPB, 0, stream>>>(Wk + (size_t)l * Cc * Cc, qt + Cc * Cc,     Cc, Cc);
        k_cvtT32<<<dim3(Cc/32, Cc/32), TPB, 0, stream>>>(Wv + (size_t)l * Cc * Cc, qt + 2 * Cc * Cc, Cc, Cc);
        k_cvtT32<<<dim3(Cc/32, Cc/32), TPB, 0, stream>>>(Wo + (size_t)l * Cc * Cc, Wot + (size_t)l * Cc * Cc, Cc, Cc);
        k_cvtT32<<<dim3(Cc/32, FF/32), TPB, 0, stream>>>(W1 + (size_t)l * Cc * FF, W1t + (size_t)l * FF * Cc, Cc, FF);
        k_cvtT32<<<dim3(FF/32, Cc/32), TPB, 0, stream>>>(W2 + (size_t)l * FF * Cc, W2t + (size_t)l * Cc * FF, FF, Cc);
    }
    k_cvtT<<<(Cc * Vv + 255) / 256, TPB, 0, stream>>>(Wlm, Wlmt, Cc, Vv);

    k_embed<<<((long)NT * Cc + 255) / 256, TPB, 0, stream>>>(idx, tok, pos, x);

    for (int l = 0; l < Ll; ++l) {
        k_ln<<<NT / 4, TPB, 0, stream>>>(x, ln1g + l * Cc, ln1b + l * Cc, h);
        dim3 gqkv(NT / 64, CQ / 64);
        k_gemm_bt<0><<<gqkv, TPB, 0, stream>>>(h, Wqkvt + (size_t)l * CQ * Cc,
                                               nullptr, nullptr, qkvb, NT, CQ, Cc);
        k_attn_mfma<<<dim3(4, Hh, Bb), TPB, 0, stream>>>(qkvb, ab);
        dim3 go(NT / 64, Cc / 64);
        k_gemm_bt<2><<<go, TPB, 0, stream>>>(ab, Wot + (size_t)l * Cc * Cc,
                                             bo + l * Cc, x, x, NT, Cc, Cc);
        k_ln<<<NT / 4, TPB, 0, stream>>>(x, ln2g + l * Cc, ln2b + l * Cc, h);
        dim3 g1(NT / 64, FF / 64);
        k_gemm_bt<1><<<g1, TPB, 0, stream>>>(h, W1t + (size_t)l * FF * Cc,
                                             b1 + l * FF, nullptr, fb, NT, FF, Cc);
        dim3 g2(NT / 64, Cc / 64);
        k_gemm_bt<2><<<g2, TPB, 0, stream>>>(fb, W2t + (size_t)l * Cc * FF,
                                             b2 + l * Cc, x, x, NT, Cc, FF);
    }
    k_ln<<<NT / 4, TPB, 0, stream>>>(x, lnfg, lnfb, h);
    k_lmhead<<<NT / 4, TPB, 0, stream>>>(h, Wlmt, blm, (float*)d_out);
}

// Round 7
// 492.823 us; speedup vs baseline: 10.7740x; 1.5003x over previous
//
#include <hip/hip_runtime.h>

#define Bb 64
#define Tt 256
#define Cc 384
#define Ll 3
#define Hh 6
#define HD 64
#define Vv 65
#define FF 1536
#define NT (Bb*Tt)        // 16384 tokens
#define CQ 1152           // fused qkv width
#define LDP 72            // attn LDS row stride (u16)

typedef unsigned short u16;
typedef unsigned int   u32;
typedef __attribute__((ext_vector_type(8))) short bf16x8;
typedef __attribute__((ext_vector_type(4))) float f32x4;

__device__ __forceinline__ float bf2f(u16 u) {
    u32 v = ((u32)u) << 16; float f; __builtin_memcpy(&f, &v, 4); return f;
}
__device__ __forceinline__ u16 f2bf(float f) {
    u32 u; __builtin_memcpy(&u, &f, 4);
    u = (u + 0x7fffu + ((u >> 16) & 1u)) >> 16;
    return (u16)u;
}
__device__ __forceinline__ void gload16(const void* g, void* l) {
    __builtin_amdgcn_global_load_lds(
        (const __attribute__((address_space(1))) u32*)g,
        (__attribute__((address_space(3))) u32*)l, 16, 0, 0);
}

// ---------------- embedding ----------------
__global__ void k_embed(const int* __restrict__ idx, const float* __restrict__ tok,
                        const float* __restrict__ pos, float* __restrict__ x)
{
    long i = (long)blockIdx.x * 256 + threadIdx.x;
    if (i >= (long)NT * Cc) return;
    int c  = (int)(i % Cc);
    int bt = (int)(i / Cc);
    int t  = bt % Tt;
    x[i] = tok[idx[bt] * Cc + c] + pos[t * Cc + c];
}

// ---------------- layernorm: fp32 in -> bf16 out, one wave per row ----------------
__global__ __launch_bounds__(256) void k_ln(const float* __restrict__ x,
    const float* __restrict__ g, const float* __restrict__ b, u16* __restrict__ h)
{
    int row  = (int)((blockIdx.x * 256 + threadIdx.x) >> 6);
    int lane = threadIdx.x & 63;
    const float* xr = x + (long)row * Cc;
    float v[6]; float s = 0.f;
    #pragma unroll
    for (int j = 0; j < 6; ++j) { v[j] = xr[lane + 64 * j]; s += v[j]; }
    #pragma unroll
    for (int m = 32; m; m >>= 1) s += __shfl_xor(s, m, 64);
    float mean = s * (1.f / 384.f);
    float q = 0.f;
    #pragma unroll
    for (int j = 0; j < 6; ++j) { float d = v[j] - mean; q += d * d; }
    #pragma unroll
    for (int m = 32; m; m >>= 1) q += __shfl_xor(q, m, 64);
    float rstd = rsqrtf(q * (1.f / 384.f) + 1e-5f);
    u16* hr = h + (long)row * Cc;
    #pragma unroll
    for (int j = 0; j < 6; ++j) {
        int c = lane + 64 * j;
        hr[c] = f2bf((v[j] - mean) * rstd * g[c] + b[c]);
    }
}

// ---------------- fused weight convert+transpose (all 18 big matrices, one launch) ----------------
// tiles: t<1728 : 12 square mats [384x384], 144 tiles each (Wq,Wk,Wv x3 layers, Wo x3)
//        t<3456 : 3 x W1 [384x1536], 576 tiles each
//        else   : 3 x W2 [1536x384], 576 tiles each
__global__ __launch_bounds__(256) void k_cvtT_all(
    const float* __restrict__ Wq, const float* __restrict__ Wk,
    const float* __restrict__ Wv, const float* __restrict__ Wo,
    const float* __restrict__ W1, const float* __restrict__ W2,
    u16* __restrict__ Wqkvt, u16* __restrict__ Wot,
    u16* __restrict__ W1t, u16* __restrict__ W2t)
{
    int t = blockIdx.x;
    const float* src; u16* dst; int K, N, tt;
    if (t < 1728) {
        int m = t / 144; tt = t % 144; K = Cc; N = Cc;
        if (m < 9) {
            int l = m / 3, q = m % 3;
            src = (q == 0 ? Wq : q == 1 ? Wk : Wv) + (size_t)l * Cc * Cc;
            dst = Wqkvt + (size_t)l * CQ * Cc + (size_t)q * Cc * Cc;
        } else {
            int l = m - 9;
            src = Wo + (size_t)l * Cc * Cc;
            dst = Wot + (size_t)l * Cc * Cc;
        }
    } else if (t < 3456) {
        int u = t - 1728; int l = u / 576; tt = u % 576; K = Cc; N = FF;
        src = W1 + (size_t)l * Cc * FF; dst = W1t + (size_t)l * FF * Cc;
    } else {
        int u = t - 3456; int l = u / 576; tt = u % 576; K = FF; N = Cc;
        src = W2 + (size_t)l * FF * Cc; dst = W2t + (size_t)l * Cc * FF;
    }
    int nk = K / 32;
    int kt = (tt % nk) * 32, nt = (tt / nk) * 32;
    __shared__ u16 tile[32][33];
    int tx = threadIdx.x & 31, ty = threadIdx.x >> 5;
    #pragma unroll
    for (int r = 0; r < 4; ++r)
        tile[ty + 8 * r][tx] = f2bf(src[(long)(kt + ty + 8 * r) * N + nt + tx]);
    __syncthreads();
    #pragma unroll
    for (int r = 0; r < 4; ++r)
        dst[(long)(nt + ty + 8 * r) * K + kt + tx] = tile[tx][ty + 8 * r];
}

// Wlm: [384][65] f32 -> padded [128][384] bf16 (zeros beyond col 65)
__global__ void k_cvtT_lm(const float* __restrict__ W, u16* __restrict__ Wt)
{
    int i = blockIdx.x * 256 + threadIdx.x;
    if (i >= 128 * Cc) return;
    int k = i % Cc, n = i / Cc;
    Wt[i] = (n < Vv) ? f2bf(W[(long)k * Vv + n]) : (u16)0;
}

// ---------------- 128x128 MFMA GEMM, global_load_lds staging, XOR-swizzled LDS ----------------
// C[M,N] = epi(A[M,K] @ Bt[N,K]^T). BK=64. 256 thr = 4 waves (2x2), 64x64 per wave.
// LDS logical tile [128 rows][64 cols u16]; element (row,c) stored at byte
// row*128 + (((c>>3) ^ (row&7))<<4) + (c&7)*2  -- linear dst for global_load_lds,
// source column pre-swizzled per lane, frag reads apply the same XOR.
// EPI 0: ->bf16; 1: +bias,relu ->bf16; 2: +bias,+R ->f32; 3: +bias, col<Nout ->f32 (stride Nout)
template<int EPI>
__global__ __launch_bounds__(256) void k_gemm128(
    const u16* __restrict__ A, const u16* __restrict__ Bt,
    const float* __restrict__ bias, const float* __restrict__ R,
    void* __restrict__ Cout, int M, int N, int K, int Nout)
{
    __shared__ __align__(16) u16 As[128 * 64];
    __shared__ __align__(16) u16 Bs[128 * 64];
    const int bm = blockIdx.x * 128;
    const int bn = blockIdx.y * 128;
    const int tid = threadIdx.x;
    const int lane = tid & 63, w = tid >> 6;
    const int wr = w >> 1, wc = w & 1;
    const int l15 = lane & 15, g = lane >> 4;
    const int lr = lane >> 3;                  // row within 8-row segment
    const int lc = ((lane & 7) ^ lr) * 8;      // pre-swizzled source column (u16)

    f32x4 acc[4][4] = {};
    // per-lane global bases for segment s=0 of this wave (segments w*4 .. w*4+3)
    const u16* Ag = A  + (long)(bm + w * 32 + lr) * K + lc;
    const u16* Bg = Bt + (long)(bn + w * 32 + lr) * K + lc;
    u16* Ad = As + (w * 4) * 512;              // 1KB per segment
    u16* Bd = Bs + (w * 4) * 512;

    for (int k0 = 0; k0 < K; k0 += 64) {
        #pragma unroll
        for (int s = 0; s < 4; ++s) {
            gload16(Ag + (long)s * 8 * K + k0, Ad + s * 512);
            gload16(Bg + (long)s * 8 * K + k0, Bd + s * 512);
        }
        __syncthreads();
        #pragma unroll
        for (int h = 0; h < 2; ++h) {
            const int cs = h * 4 + g;
            bf16x8 af[4], bfr[4];
            #pragma unroll
            for (int mi = 0; mi < 4; ++mi) {
                int row = wr * 64 + mi * 16 + l15;
                af[mi] = *(const bf16x8*)((const char*)As + row * 128 + ((cs ^ (row & 7)) << 4));
            }
            #pragma unroll
            for (int ni = 0; ni < 4; ++ni) {
                int row = wc * 64 + ni * 16 + l15;
                bfr[ni] = *(const bf16x8*)((const char*)Bs + row * 128 + ((cs ^ (row & 7)) << 4));
            }
            #pragma unroll
            for (int mi = 0; mi < 4; ++mi)
            #pragma unroll
            for (int ni = 0; ni < 4; ++ni)
                acc[mi][ni] = __builtin_amdgcn_mfma_f32_16x16x32_bf16(af[mi], bfr[ni], acc[mi][ni], 0, 0, 0);
        }
        __syncthreads();
    }
    #pragma unroll
    for (int mi = 0; mi < 4; ++mi)
    #pragma unroll
    for (int ni = 0; ni < 4; ++ni)
    #pragma unroll
    for (int i = 0; i < 4; ++i) {
        int row = bm + wr * 64 + mi * 16 + g * 4 + i;
        int col = bn + wc * 64 + ni * 16 + l15;
        float v = acc[mi][ni][i];
        if constexpr (EPI == 0) {
            ((u16*)Cout)[(long)row * N + col] = f2bf(v);
        } else if constexpr (EPI == 1) {
            v = fmaxf(v + bias[col], 0.f);
            ((u16*)Cout)[(long)row * N + col] = f2bf(v);
        } else if constexpr (EPI == 2) {
            long o = (long)row * N + col;
            ((float*)Cout)[o] = v + bias[col] + R[o];
        } else {
            if (col < Nout)
                ((float*)Cout)[(long)row * Nout + col] = v + bias[col];
        }
    }
}

// ---------------- MFMA flash attention (unchanged, validated round 6) ----------------
__global__ __launch_bounds__(256) void k_attn_mfma(const u16* __restrict__ qkv,
                                                   u16* __restrict__ att)
{
    __shared__ __align__(16) u16 ks[64][LDP];
    __shared__ __align__(16) u16 vt[64][LDP];
    __shared__ __align__(16) u16 pt[4][16][LDP];
    const int qt = blockIdx.x, hh = blockIdx.y, b = blockIdx.z;
    const int tid = threadIdx.x, lane = tid & 63, w = tid >> 6;
    const int l15 = lane & 15, g = lane >> 4;
    const int q0 = qt * 64;
    const long tokbase = (long)b * Tt;
    const float scale = 0.051031036307982884f;

    bf16x8 qa0, qa1;
    {
        const u16* qp = qkv + (tokbase + q0 + w * 16 + l15) * CQ + hh * HD + g * 8;
        qa0 = *(const bf16x8*)(qp);
        qa1 = *(const bf16x8*)(qp + 32);
    }
    f32x4 o[4] = {};
    float mrow[4] = {-1e30f, -1e30f, -1e30f, -1e30f};
    float lrow[4] = {0.f, 0.f, 0.f, 0.f};

    for (int kt = 0; kt <= qt; ++kt) {
        {
            int key = tid >> 2, c0 = (tid & 3) * 16;
            const u16* kg = qkv + (tokbase + kt * 64 + key) * CQ + Cc     + hh * HD + c0;
            const u16* vg = qkv + (tokbase + kt * 64 + key) * CQ + 2 * Cc + hh * HD + c0;
            *(bf16x8*)&ks[key][c0]     = *(const bf16x8*)kg;
            *(bf16x8*)&ks[key][c0 + 8] = *(const bf16x8*)(kg + 8);
            bf16x8 v0 = *(const bf16x8*)vg;
            bf16x8 v1 = *(const bf16x8*)(vg + 8);
            #pragma unroll
            for (int j = 0; j < 8; ++j) vt[c0 + j][key]     = (u16)v0[j];
            #pragma unroll
            for (int j = 0; j < 8; ++j) vt[c0 + 8 + j][key] = (u16)v1[j];
        }
        __syncthreads();
        f32x4 s[4] = {};
        #pragma unroll
        for (int c = 0; c < 4; ++c) {
            bf16x8 kb0 = *(const bf16x8*)&ks[c * 16 + l15][g * 8];
            bf16x8 kb1 = *(const bf16x8*)&ks[c * 16 + l15][32 + g * 8];
            s[c] = __builtin_amdgcn_mfma_f32_16x16x32_bf16(qa0, kb0, s[c], 0, 0, 0);
            s[c] = __builtin_amdgcn_mfma_f32_16x16x32_bf16(qa1, kb1, s[c], 0, 0, 0);
        }
        const bool diag = (kt == qt);
        #pragma unroll
        for (int c = 0; c < 4; ++c)
        #pragma unroll
        for (int i = 0; i < 4; ++i) {
            float v = s[c][i] * scale;
            if (diag && (c * 16 + l15 > w * 16 + 4 * g + i)) v = -1e30f;
            s[c][i] = v;
        }
        #pragma unroll
        for (int i = 0; i < 4; ++i) {
            float m0 = fmaxf(fmaxf(s[0][i], s[1][i]), fmaxf(s[2][i], s[3][i]));
            #pragma unroll
            for (int mm = 1; mm < 16; mm <<= 1) m0 = fmaxf(m0, __shfl_xor(m0, mm, 64));
            float mn = fmaxf(mrow[i], m0);
            float alpha = __expf(mrow[i] - mn);
            mrow[i] = mn;
            float sum = 0.f;
            #pragma unroll
            for (int c = 0; c < 4; ++c) {
                float p = __expf(s[c][i] - mn);
                s[c][i] = p;
                sum += p;
            }
            #pragma unroll
            for (int mm = 1; mm < 16; mm <<= 1) sum += __shfl_xor(sum, mm, 64);
            lrow[i] = lrow[i] * alpha + sum;
            #pragma unroll
            for (int d = 0; d < 4; ++d) o[d][i] *= alpha;
        }
        #pragma unroll
        for (int c = 0; c < 4; ++c)
        #pragma unroll
        for (int i = 0; i < 4; ++i)
            pt[w][g * 4 + i][c * 16 + l15] = f2bf(s[c][i]);
        bf16x8 pa0 = *(const bf16x8*)&pt[w][l15][g * 8];
        bf16x8 pa1 = *(const bf16x8*)&pt[w][l15][32 + g * 8];
        #pragma unroll
        for (int d = 0; d < 4; ++d) {
            bf16x8 vb0 = *(const bf16x8*)&vt[d * 16 + l15][g * 8];
            bf16x8 vb1 = *(const bf16x8*)&vt[d * 16 + l15][32 + g * 8];
            o[d] = __builtin_amdgcn_mfma_f32_16x16x32_bf16(pa0, vb0, o[d], 0, 0, 0);
            o[d] = __builtin_amdgcn_mfma_f32_16x16x32_bf16(pa1, vb1, o[d], 0, 0, 0);
        }
        __syncthreads();
    }
    #pragma unroll
    for (int i = 0; i < 4; ++i) {
        float inv = 1.f / lrow[i];
        int row = q0 + w * 16 + g * 4 + i;
        u16* ap = att + (tokbase + row) * Cc + hh * HD;
        #pragma unroll
        for (int d = 0; d < 4; ++d)
            ap[d * 16 + l15] = f2bf(o[d][i] * inv);
    }
}

extern "C" void kernel_launch(void* const* d_in, const int* in_sizes, int n_in,
                              void* d_out, int out_size, void* d_ws, size_t ws_size,
                              hipStream_t stream)
{
    (void)in_sizes; (void)n_in; (void)out_size; (void)ws_size;
    const int*   idx  = (const int*)d_in[0];
    const float* tok  = (const float*)d_in[1];
    const float* pos  = (const float*)d_in[2];
    const float* Wq   = (const float*)d_in[3];
    const float* Wk   = (const float*)d_in[4];
    const float* Wv   = (const float*)d_in[5];
    const float* Wo   = (const float*)d_in[6];
    const float* bo   = (const float*)d_in[7];
    const float* ln1g = (const float*)d_in[8];
    const float* ln1b = (const float*)d_in[9];
    const float* ln2g = (const float*)d_in[10];
    const float* ln2b = (const float*)d_in[11];
    const float* W1   = (const float*)d_in[12];
    const float* b1   = (const float*)d_in[13];
    const float* W2   = (const float*)d_in[14];
    const float* b2   = (const float*)d_in[15];
    const float* lnfg = (const float*)d_in[16];
    const float* lnfb = (const float*)d_in[17];
    const float* Wlm  = (const float*)d_in[18];
    const float* blm  = (const float*)d_in[19];

    char* w = (char*)d_ws;
    auto carve = [&](size_t bytes) { char* p = w; w += (bytes + 255) & ~(size_t)255; return p; };
    float* x   = (float*)carve((size_t)NT * Cc * 4);
    u16*  big  = (u16*)carve((size_t)NT * FF * 2);
    u16*  h    = (u16*)carve((size_t)NT * Cc * 2);
    u16*  ab   = (u16*)carve((size_t)NT * Cc * 2);
    u16*  Wqkvt= (u16*)carve((size_t)Ll * CQ * Cc * 2);
    u16*  Wot  = (u16*)carve((size_t)Ll * Cc * Cc * 2);
    u16*  W1t  = (u16*)carve((size_t)Ll * FF * Cc * 2);
    u16*  W2t  = (u16*)carve((size_t)Ll * Cc * FF * 2);
    u16*  Wlmt = (u16*)carve((size_t)128 * Cc * 2);
    u16*  qkvb = big;
    u16*  fb   = big;

    const int TPB = 256;
    k_cvtT_all<<<5184, TPB, 0, stream>>>(Wq, Wk, Wv, Wo, W1, W2, Wqkvt, Wot, W1t, W2t);
    k_cvtT_lm<<<(128 * Cc + 255) / 256, TPB, 0, stream>>>(Wlm, Wlmt);
    k_embed<<<((long)NT * Cc + 255) / 256, TPB, 0, stream>>>(idx, tok, pos, x);

    for (int l = 0; l < Ll; ++l) {
        k_ln<<<NT / 4, TPB, 0, stream>>>(x, ln1g + l * Cc, ln1b + l * Cc, h);
        k_gemm128<0><<<dim3(NT / 128, CQ / 128), TPB, 0, stream>>>(
            h, Wqkvt + (size_t)l * CQ * Cc, nullptr, nullptr, qkvb, NT, CQ, Cc, CQ);
        k_attn_mfma<<<dim3(4, Hh, Bb), TPB, 0, stream>>>(qkvb, ab);
        k_gemm128<2><<<dim3(NT / 128, Cc / 128), TPB, 0, stream>>>(
            ab, Wot + (size_t)l * Cc * Cc, bo + l * Cc, x, x, NT, Cc, Cc, Cc);
        k_ln<<<NT / 4, TPB, 0, stream>>>(x, ln2g + l * Cc, ln2b + l * Cc, h);
        k_gemm128<1><<<dim3(NT / 128, FF / 128), TPB, 0, stream>>>(
            h, W1t + (size_t)l * FF * Cc, b1 + l * FF, nullptr, fb, NT, FF, Cc, FF);
        k_gemm128<2><<<dim3(NT / 128, Cc / 128), TPB, 0, stream>>>(
            fb, W2t + (size_t)l * Cc * FF, b2 + l * Cc, x, x, NT, Cc, FF, Cc);
    }
    k_ln<<<NT / 4, TPB, 0, stream>>>(x, lnfg, lnfb, h);
    k_gemm128<3><<<dim3(NT / 128, 1), TPB, 0, stream>>>(
        h, Wlmt, blm, nullptr, (float*)d_out, NT, 128, Cc, Vv);
}

// Round 8
// 462.801 us; speedup vs baseline: 11.4730x; 1.0649x over previous
//
#include <hip/hip_runtime.h>

#define Bb 64
#define Tt 256
#define Cc 384
#define Ll 3
#define Hh 6
#define HD 64
#define Vv 65
#define FF 1536
#define NT (Bb*Tt)        // 16384 tokens
#define CQ 1152           // fused qkv width
#define LDP 72            // attn LDS row stride (u16)

typedef unsigned short u16;
typedef unsigned int   u32;
typedef __attribute__((ext_vector_type(8))) short bf16x8;
typedef __attribute__((ext_vector_type(4))) float f32x4;

__device__ __forceinline__ float bf2f(u16 u) {
    u32 v = ((u32)u) << 16; float f; __builtin_memcpy(&f, &v, 4); return f;
}
__device__ __forceinline__ u16 f2bf(float f) {
    u32 u; __builtin_memcpy(&u, &f, 4);
    u = (u + 0x7fffu + ((u >> 16) & 1u)) >> 16;
    return (u16)u;
}
__device__ __forceinline__ void gload16(const void* g, void* l) {
    __builtin_amdgcn_global_load_lds(
        (const __attribute__((address_space(1))) u32*)g,
        (__attribute__((address_space(3))) u32*)l, 16, 0, 0);
}

// ---------------- embedding ----------------
__global__ void k_embed(const int* __restrict__ idx, const float* __restrict__ tok,
                        const float* __restrict__ pos, float* __restrict__ x)
{
    long i = (long)blockIdx.x * 256 + threadIdx.x;
    if (i >= (long)NT * Cc) return;
    int c  = (int)(i % Cc);
    int bt = (int)(i / Cc);
    int t  = bt % Tt;
    x[i] = tok[idx[bt] * Cc + c] + pos[t * Cc + c];
}

// ---------------- layernorm: fp32 in -> bf16 out, one wave per row ----------------
__global__ __launch_bounds__(256) void k_ln(const float* __restrict__ x,
    const float* __restrict__ g, const float* __restrict__ b, u16* __restrict__ h)
{
    int row  = (int)((blockIdx.x * 256 + threadIdx.x) >> 6);
    int lane = threadIdx.x & 63;
    const float* xr = x + (long)row * Cc;
    float v[6]; float s = 0.f;
    #pragma unroll
    for (int j = 0; j < 6; ++j) { v[j] = xr[lane + 64 * j]; s += v[j]; }
    #pragma unroll
    for (int m = 32; m; m >>= 1) s += __shfl_xor(s, m, 64);
    float mean = s * (1.f / 384.f);
    float q = 0.f;
    #pragma unroll
    for (int j = 0; j < 6; ++j) { float d = v[j] - mean; q += d * d; }
    #pragma unroll
    for (int m = 32; m; m >>= 1) q += __shfl_xor(q, m, 64);
    float rstd = rsqrtf(q * (1.f / 384.f) + 1e-5f);
    u16* hr = h + (long)row * Cc;
    #pragma unroll
    for (int j = 0; j < 6; ++j) {
        int c = lane + 64 * j;
        hr[c] = f2bf((v[j] - mean) * rstd * g[c] + b[c]);
    }
}

// ---------------- fused weight convert+transpose (all 18 big matrices) ----------------
__global__ __launch_bounds__(256) void k_cvtT_all(
    const float* __restrict__ Wq, const float* __restrict__ Wk,
    const float* __restrict__ Wv, const float* __restrict__ Wo,
    const float* __restrict__ W1, const float* __restrict__ W2,
    u16* __restrict__ Wqkvt, u16* __restrict__ Wot,
    u16* __restrict__ W1t, u16* __restrict__ W2t)
{
    int t = blockIdx.x;
    const float* src; u16* dst; int K, N, tt;
    if (t < 1728) {
        int m = t / 144; tt = t % 144; K = Cc; N = Cc;
        if (m < 9) {
            int l = m / 3, q = m % 3;
            src = (q == 0 ? Wq : q == 1 ? Wk : Wv) + (size_t)l * Cc * Cc;
            dst = Wqkvt + (size_t)l * CQ * Cc + (size_t)q * Cc * Cc;
        } else {
            int l = m - 9;
            src = Wo + (size_t)l * Cc * Cc;
            dst = Wot + (size_t)l * Cc * Cc;
        }
    } else if (t < 3456) {
        int u = t - 1728; int l = u / 576; tt = u % 576; K = Cc; N = FF;
        src = W1 + (size_t)l * Cc * FF; dst = W1t + (size_t)l * FF * Cc;
    } else {
        int u = t - 3456; int l = u / 576; tt = u % 576; K = FF; N = Cc;
        src = W2 + (size_t)l * FF * Cc; dst = W2t + (size_t)l * Cc * FF;
    }
    int nk = K / 32;
    int kt = (tt % nk) * 32, nt = (tt / nk) * 32;
    __shared__ u16 tile[32][33];
    int tx = threadIdx.x & 31, ty = threadIdx.x >> 5;
    #pragma unroll
    for (int r = 0; r < 4; ++r)
        tile[ty + 8 * r][tx] = f2bf(src[(long)(kt + ty + 8 * r) * N + nt + tx]);
    __syncthreads();
    #pragma unroll
    for (int r = 0; r < 4; ++r)
        dst[(long)(nt + ty + 8 * r) * K + kt + tx] = tile[tx][ty + 8 * r];
}

// Wlm: [384][65] f32 -> padded [128][384] bf16
__global__ void k_cvtT_lm(const float* __restrict__ W, u16* __restrict__ Wt)
{
    int i = blockIdx.x * 256 + threadIdx.x;
    if (i >= 128 * Cc) return;
    int k = i % Cc, n = i / Cc;
    Wt[i] = (n < Vv) ? f2bf(W[(long)k * Vv + n]) : (u16)0;
}

// ---------------- 128x128 MFMA GEMM (wide N), swizzled global_load_lds ----------------
// EPI 0: ->bf16; 1: +bias,relu ->bf16; 2: +bias,+R ->f32; 3: +bias, col<Nout ->f32
template<int EPI>
__global__ __launch_bounds__(256) void k_gemm128(
    const u16* __restrict__ A, const u16* __restrict__ Bt,
    const float* __restrict__ bias, const float* __restrict__ R,
    void* __restrict__ Cout, int M, int N, int K, int Nout)
{
    __shared__ __align__(16) u16 As[128 * 64];
    __shared__ __align__(16) u16 Bs[128 * 64];
    const int bm = blockIdx.x * 128;
    const int bn = blockIdx.y * 128;
    const int tid = threadIdx.x;
    const int lane = tid & 63, w = tid >> 6;
    const int wr = w >> 1, wc = w & 1;
    const int l15 = lane & 15, g = lane >> 4;
    const int lr = lane >> 3;
    const int lc = ((lane & 7) ^ lr) * 8;      // pre-swizzled source column

    f32x4 acc[4][4] = {};
    const u16* Ag = A  + (long)(bm + w * 32 + lr) * K + lc;
    const u16* Bg = Bt + (long)(bn + w * 32 + lr) * K + lc;
    u16* Ad = As + (w * 4) * 512;
    u16* Bd = Bs + (w * 4) * 512;

    for (int k0 = 0; k0 < K; k0 += 64) {
        #pragma unroll
        for (int s = 0; s < 4; ++s) {
            gload16(Ag + (long)s * 8 * K + k0, Ad + s * 512);
            gload16(Bg + (long)s * 8 * K + k0, Bd + s * 512);
        }
        __syncthreads();
        #pragma unroll
        for (int h = 0; h < 2; ++h) {
            const int cs = h * 4 + g;
            bf16x8 af[4], bfr[4];
            #pragma unroll
            for (int mi = 0; mi < 4; ++mi) {
                int row = wr * 64 + mi * 16 + l15;
                af[mi] = *(const bf16x8*)((const char*)As + row * 128 + ((cs ^ (row & 7)) << 4));
            }
            #pragma unroll
            for (int ni = 0; ni < 4; ++ni) {
                int row = wc * 64 + ni * 16 + l15;
                bfr[ni] = *(const bf16x8*)((const char*)Bs + row * 128 + ((cs ^ (row & 7)) << 4));
            }
            #pragma unroll
            for (int mi = 0; mi < 4; ++mi)
            #pragma unroll
            for (int ni = 0; ni < 4; ++ni)
                acc[mi][ni] = __builtin_amdgcn_mfma_f32_16x16x32_bf16(af[mi], bfr[ni], acc[mi][ni], 0, 0, 0);
        }
        __syncthreads();
    }
    #pragma unroll
    for (int mi = 0; mi < 4; ++mi)
    #pragma unroll
    for (int ni = 0; ni < 4; ++ni)
    #pragma unroll
    for (int i = 0; i < 4; ++i) {
        int row = bm + wr * 64 + mi * 16 + g * 4 + i;
        int col = bn + wc * 64 + ni * 16 + l15;
        float v = acc[mi][ni][i];
        if constexpr (EPI == 0) {
            ((u16*)Cout)[(long)row * N + col] = f2bf(v);
        } else if constexpr (EPI == 1) {
            v = fmaxf(v + bias[col], 0.f);
            ((u16*)Cout)[(long)row * N + col] = f2bf(v);
        } else if constexpr (EPI == 2) {
            long o = (long)row * N + col;
            ((float*)Cout)[o] = v + bias[col] + R[o];
        } else {
            if (col < Nout)
                ((float*)Cout)[(long)row * Nout + col] = v + bias[col];
        }
    }
}

// ---------------- 128x64 MFMA GEMM (narrow N: Wo, W2, lm-head) ----------------
// 4 waves, each 32 rows x 64 cols. Grid (M/128, N/64). Same swizzle scheme.
template<int EPI>
__global__ __launch_bounds__(256) void k_gemm_n64(
    const u16* __restrict__ A, const u16* __restrict__ Bt,
    const float* __restrict__ bias, const float* __restrict__ R,
    void* __restrict__ Cout, int M, int N, int K, int Nout)
{
    __shared__ __align__(16) u16 As[128 * 64];
    __shared__ __align__(16) u16 Bs[64 * 64];
    const int bm = blockIdx.x * 128;
    const int bn = blockIdx.y * 64;
    const int tid = threadIdx.x;
    const int lane = tid & 63, w = tid >> 6;
    const int l15 = lane & 15, g = lane >> 4;
    const int lr = lane >> 3;
    const int lc = ((lane & 7) ^ lr) * 8;

    f32x4 acc[2][4] = {};
    const u16* Ag = A  + (long)(bm + w * 32 + lr) * K + lc;   // A segs w*4..w*4+3
    const u16* Bg = Bt + (long)(bn + w * 16 + lr) * K + lc;   // B segs w*2..w*2+1
    u16* Ad = As + (w * 4) * 512;
    u16* Bd = Bs + (w * 2) * 512;

    for (int k0 = 0; k0 < K; k0 += 64) {
        #pragma unroll
        for (int s = 0; s < 4; ++s)
            gload16(Ag + (long)s * 8 * K + k0, Ad + s * 512);
        #pragma unroll
        for (int t = 0; t < 2; ++t)
            gload16(Bg + (long)t * 8 * K + k0, Bd + t * 512);
        __syncthreads();
        #pragma unroll
        for (int h = 0; h < 2; ++h) {
            const int cs = h * 4 + g;
            bf16x8 af[2], bfr[4];
            #pragma unroll
            for (int mi = 0; mi < 2; ++mi) {
                int row = w * 32 + mi * 16 + l15;
                af[mi] = *(const bf16x8*)((const char*)As + row * 128 + ((cs ^ (row & 7)) << 4));
            }
            #pragma unroll
            for (int ni = 0; ni < 4; ++ni) {
                int row = ni * 16 + l15;
                bfr[ni] = *(const bf16x8*)((const char*)Bs + row * 128 + ((cs ^ (row & 7)) << 4));
            }
            #pragma unroll
            for (int mi = 0; mi < 2; ++mi)
            #pragma unroll
            for (int ni = 0; ni < 4; ++ni)
                acc[mi][ni] = __builtin_amdgcn_mfma_f32_16x16x32_bf16(af[mi], bfr[ni], acc[mi][ni], 0, 0, 0);
        }
        __syncthreads();
    }
    #pragma unroll
    for (int mi = 0; mi < 2; ++mi)
    #pragma unroll
    for (int ni = 0; ni < 4; ++ni)
    #pragma unroll
    for (int i = 0; i < 4; ++i) {
        int row = bm + w * 32 + mi * 16 + g * 4 + i;
        int col = bn + ni * 16 + l15;
        float v = acc[mi][ni][i];
        if constexpr (EPI == 0) {
            ((u16*)Cout)[(long)row * N + col] = f2bf(v);
        } else if constexpr (EPI == 1) {
            v = fmaxf(v + bias[col], 0.f);
            ((u16*)Cout)[(long)row * N + col] = f2bf(v);
        } else if constexpr (EPI == 2) {
            long o = (long)row * N + col;
            ((float*)Cout)[o] = v + bias[col] + R[o];
        } else {
            if (col < Nout)
                ((float*)Cout)[(long)row * Nout + col] = v + bias[col];
        }
    }
}

// ---------------- MFMA flash attention (validated) ----------------
__global__ __launch_bounds__(256) void k_attn_mfma(const u16* __restrict__ qkv,
                                                   u16* __restrict__ att)
{
    __shared__ __align__(16) u16 ks[64][LDP];
    __shared__ __align__(16) u16 vt[64][LDP];
    __shared__ __align__(16) u16 pt[4][16][LDP];
    const int qt = blockIdx.x, hh = blockIdx.y, b = blockIdx.z;
    const int tid = threadIdx.x, lane = tid & 63, w = tid >> 6;
    const int l15 = lane & 15, g = lane >> 4;
    const int q0 = qt * 64;
    const long tokbase = (long)b * Tt;
    const float scale = 0.051031036307982884f;

    bf16x8 qa0, qa1;
    {
        const u16* qp = qkv + (tokbase + q0 + w * 16 + l15) * CQ + hh * HD + g * 8;
        qa0 = *(const bf16x8*)(qp);
        qa1 = *(const bf16x8*)(qp + 32);
    }
    f32x4 o[4] = {};
    float mrow[4] = {-1e30f, -1e30f, -1e30f, -1e30f};
    float lrow[4] = {0.f, 0.f, 0.f, 0.f};

    for (int kt = 0; kt <= qt; ++kt) {
        {
            int key = tid >> 2, c0 = (tid & 3) * 16;
            const u16* kg = qkv + (tokbase + kt * 64 + key) * CQ + Cc     + hh * HD + c0;
            const u16* vg = qkv + (tokbase + kt * 64 + key) * CQ + 2 * Cc + hh * HD + c0;
            *(bf16x8*)&ks[key][c0]     = *(const bf16x8*)kg;
            *(bf16x8*)&ks[key][c0 + 8] = *(const bf16x8*)(kg + 8);
            bf16x8 v0 = *(const bf16x8*)vg;
            bf16x8 v1 = *(const bf16x8*)(vg + 8);
            #pragma unroll
            for (int j = 0; j < 8; ++j) vt[c0 + j][key]     = (u16)v0[j];
            #pragma unroll
            for (int j = 0; j < 8; ++j) vt[c0 + 8 + j][key] = (u16)v1[j];
        }
        __syncthreads();
        f32x4 s[4] = {};
        #pragma unroll
        for (int c = 0; c < 4; ++c) {
            bf16x8 kb0 = *(const bf16x8*)&ks[c * 16 + l15][g * 8];
            bf16x8 kb1 = *(const bf16x8*)&ks[c * 16 + l15][32 + g * 8];
            s[c] = __builtin_amdgcn_mfma_f32_16x16x32_bf16(qa0, kb0, s[c], 0, 0, 0);
            s[c] = __builtin_amdgcn_mfma_f32_16x16x32_bf16(qa1, kb1, s[c], 0, 0, 0);
        }
        const bool diag = (kt == qt);
        #pragma unroll
        for (int c = 0; c < 4; ++c)
        #pragma unroll
        for (int i = 0; i < 4; ++i) {
            float v = s[c][i] * scale;
            if (diag && (c * 16 + l15 > w * 16 + 4 * g + i)) v = -1e30f;
            s[c][i] = v;
        }
        #pragma unroll
        for (int i = 0; i < 4; ++i) {
            float m0 = fmaxf(fmaxf(s[0][i], s[1][i]), fmaxf(s[2][i], s[3][i]));
            #pragma unroll
            for (int mm = 1; mm < 16; mm <<= 1) m0 = fmaxf(m0, __shfl_xor(m0, mm, 64));
            float mn = fmaxf(mrow[i], m0);
            float alpha = __expf(mrow[i] - mn);
            mrow[i] = mn;
            float sum = 0.f;
            #pragma unroll
            for (int c = 0; c < 4; ++c) {
                float p = __expf(s[c][i] - mn);
                s[c][i] = p;
                sum += p;
            }
            #pragma unroll
            for (int mm = 1; mm < 16; mm <<= 1) sum += __shfl_xor(sum, mm, 64);
            lrow[i] = lrow[i] * alpha + sum;
            #pragma unroll
            for (int d = 0; d < 4; ++d) o[d][i] *= alpha;
        }
        #pragma unroll
        for (int c = 0; c < 4; ++c)
        #pragma unroll
        for (int i = 0; i < 4; ++i)
            pt[w][g * 4 + i][c * 16 + l15] = f2bf(s[c][i]);
        bf16x8 pa0 = *(const bf16x8*)&pt[w][l15][g * 8];
        bf16x8 pa1 = *(const bf16x8*)&pt[w][l15][32 + g * 8];
        #pragma unroll
        for (int d = 0; d < 4; ++d) {
            bf16x8 vb0 = *(const bf16x8*)&vt[d * 16 + l15][g * 8];
            bf16x8 vb1 = *(const bf16x8*)&vt[d * 16 + l15][32 + g * 8];
            o[d] = __builtin_amdgcn_mfma_f32_16x16x32_bf16(pa0, vb0, o[d], 0, 0, 0);
            o[d] = __builtin_amdgcn_mfma_f32_16x16x32_bf16(pa1, vb1, o[d], 0, 0, 0);
        }
        __syncthreads();
    }
    #pragma unroll
    for (int i = 0; i < 4; ++i) {
        float inv = 1.f / lrow[i];
        int row = q0 + w * 16 + g * 4 + i;
        u16* ap = att + (tokbase + row) * Cc + hh * HD;
        #pragma unroll
        for (int d = 0; d < 4; ++d)
            ap[d * 16 + l15] = f2bf(o[d][i] * inv);
    }
}

extern "C" void kernel_launch(void* const* d_in, const int* in_sizes, int n_in,
                              void* d_out, int out_size, void* d_ws, size_t ws_size,
                              hipStream_t stream)
{
    (void)in_sizes; (void)n_in; (void)out_size; (void)ws_size;
    const int*   idx  = (const int*)d_in[0];
    const float* tok  = (const float*)d_in[1];
    const float* pos  = (const float*)d_in[2];
    const float* Wq   = (const float*)d_in[3];
    const float* Wk   = (const float*)d_in[4];
    const float* Wv   = (const float*)d_in[5];
    const float* Wo   = (const float*)d_in[6];
    const float* bo   = (const float*)d_in[7];
    const float* ln1g = (const float*)d_in[8];
    const float* ln1b = (const float*)d_in[9];
    const float* ln2g = (const float*)d_in[10];
    const float* ln2b = (const float*)d_in[11];
    const float* W1   = (const float*)d_in[12];
    const float* b1   = (const float*)d_in[13];
    const float* W2   = (const float*)d_in[14];
    const float* b2   = (const float*)d_in[15];
    const float* lnfg = (const float*)d_in[16];
    const float* lnfb = (const float*)d_in[17];
    const float* Wlm  = (const float*)d_in[18];
    const float* blm  = (const float*)d_in[19];

    char* w = (char*)d_ws;
    auto carve = [&](size_t bytes) { char* p = w; w += (bytes + 255) & ~(size_t)255; return p; };
    float* x   = (float*)carve((size_t)NT * Cc * 4);
    u16*  big  = (u16*)carve((size_t)NT * FF * 2);
    u16*  h    = (u16*)carve((size_t)NT * Cc * 2);
    u16*  ab   = (u16*)carve((size_t)NT * Cc * 2);
    u16*  Wqkvt= (u16*)carve((size_t)Ll * CQ * Cc * 2);
    u16*  Wot  = (u16*)carve((size_t)Ll * Cc * Cc * 2);
    u16*  W1t  = (u16*)carve((size_t)Ll * FF * Cc * 2);
    u16*  W2t  = (u16*)carve((size_t)Ll * Cc * FF * 2);
    u16*  Wlmt = (u16*)carve((size_t)128 * Cc * 2);
    u16*  qkvb = big;
    u16*  fb   = big;

    const int TPB = 256;
    k_cvtT_all<<<5184, TPB, 0, stream>>>(Wq, Wk, Wv, Wo, W1, W2, Wqkvt, Wot, W1t, W2t);
    k_cvtT_lm<<<(128 * Cc + 255) / 256, TPB, 0, stream>>>(Wlm, Wlmt);
    k_embed<<<((long)NT * Cc + 255) / 256, TPB, 0, stream>>>(idx, tok, pos, x);

    for (int l = 0; l < Ll; ++l) {
        k_ln<<<NT / 4, TPB, 0, stream>>>(x, ln1g + l * Cc, ln1b + l * Cc, h);
        k_gemm128<0><<<dim3(NT / 128, CQ / 128), TPB, 0, stream>>>(
            h, Wqkvt + (size_t)l * CQ * Cc, nullptr, nullptr, qkvb, NT, CQ, Cc, CQ);
        k_attn_mfma<<<dim3(4, Hh, Bb), TPB, 0, stream>>>(qkvb, ab);
        k_gemm_n64<2><<<dim3(NT / 128, Cc / 64), TPB, 0, stream>>>(
            ab, Wot + (size_t)l * Cc * Cc, bo + l * Cc, x, x, NT, Cc, Cc, Cc);
        k_ln<<<NT / 4, TPB, 0, stream>>>(x, ln2g + l * Cc, ln2b + l * Cc, h);
        k_gemm128<1><<<dim3(NT / 128, FF / 128), TPB, 0, stream>>>(
            h, W1t + (size_t)l * FF * Cc, b1 + l * FF, nullptr, fb, NT, FF, Cc, FF);
        k_gemm_n64<2><<<dim3(NT / 128, Cc / 64), TPB, 0, stream>>>(
            fb, W2t + (size_t)l * Cc * FF, b2 + l * Cc, x, x, NT, Cc, FF, Cc);
    }
    k_ln<<<NT / 4, TPB, 0, stream>>>(x, lnfg, lnfb, h);
    k_gemm_n64<3><<<dim3(NT / 128, 2), TPB, 0, stream>>>(
        h, Wlmt, blm, nullptr, (float*)d_out, NT, 128, Cc, Vv);
}